// Round 8
// baseline (263.114 us; speedup 1.0000x reference)
//
#include <hip/hip_runtime.h>

#define N_NODES 100000
#define N_EDGES 640000
#define F 128
#define NT 6250          // 16-node tiles (100000 = 6250*16 exactly)

typedef __attribute__((ext_vector_type(8))) short short8;
typedef __attribute__((ext_vector_type(4))) float float4v;

// RNE float -> bf16 bits
static __device__ __forceinline__ unsigned short f2bf(float f) {
    unsigned int u = __float_as_uint(f);
    u += 0x7fffu + ((u >> 16) & 1u);
    return (unsigned short)(u >> 16);
}

// ---------------------------------------------------------------------------
// Kernel 0: transpose+convert W1 (fp32 [256][128]) into Wt bf16 [256][128]:
//   Wt[n][k] = W1[(n&128)+k][n&127]
// n<128 rows = A-half (W1[k][n]); n>=128 = B-half. 64 KB, stays L2-hot.
// ---------------------------------------------------------------------------
__global__ __launch_bounds__(256) void prep_wt(
    const float* __restrict__ W1, unsigned short* __restrict__ Wt)
{
    int id = blockIdx.x * 256 + threadIdx.x;       // 0 .. 32767
    int n = id >> 7, k = id & 127;
    float v = W1[((n & 128) + k) * 128 + (n & 127)];
    Wt[id] = f2bf(v);
}

// ---------------------------------------------------------------------------
// Kernel 1: node projections — FUSED A+B, single pass over h.
// SESSION LAW (r4/r5/r6 evidence): all GLOBAL loads lane-contiguous;
// lane-transposes go through LDS.
//   grid = 256 blocks x 512 threads (8 waves) -> 1 block/CU, 8 waves/CU.
//   Stage FULL Wt (256x128 bf16) in LDS once; ONE barrier total.
//   Each wave streams private 16-node tiles (t = bx*8+w, stride 2048):
//     prefetch next tile's h into regs (coalesced float4) -> compute current
//     tile (16 wtiles x 4 k0 MFMA = both A and B outputs) -> convert+write
//     prefetched into the SAME private buffer (in-wave program order = safe,
//     no double buffer, no loop barriers) -> packed 8B epilogue stores.
//   mfma_16x16x32_bf16: A-frag = w_lds row (m=wcol), B-frag = h row (n=node);
//   C/D: wcol = quad*4+reg, node = l16  (verified r7 mapping).
// LDS: 69.6 KB (Wt, stride 136) + 8 x 4.37 KB (h) = 104.6 KB -> 1 block/CU.
// h read ONCE (vs twice in r7): FETCH ~76 -> ~55 MB.
// ---------------------------------------------------------------------------
__global__ __launch_bounds__(512, 1) void node_proj(
    const float* __restrict__ h, const unsigned short* __restrict__ Wt,
    const float* __restrict__ b1,
    unsigned short* __restrict__ A, unsigned short* __restrict__ B)
{
    __shared__ unsigned short w_lds[256 * 136];           // 69.6 KB
    __shared__ unsigned short h_lds[8][16 * 136 + 8];     // 8 x 4.37 KB

    const int tid  = threadIdx.x;
    const int lane = tid & 63;
    const int l16  = lane & 15;
    const int quad = lane >> 4;
    const int w    = tid >> 6;            // wave id 0..7

    // ---- stage full Wt into LDS, fully coalesced (uint4 = 8 bf16) ----
#pragma unroll
    for (int i = 0; i < 8; ++i) {
        int c = i * 512 + tid;            // uint4 chunk id, 0..4095
        int r = c >> 4, cc = c & 15;      // 16 chunks per 128-short row
        uint4 v = *(const uint4*)(Wt + (size_t)r * F + cc * 8);
        *(uint4*)&w_lds[r * 136 + cc * 8] = v;
    }
    __syncthreads();                      // the ONLY barrier

    // hoisted bias fragments (A half): col = mt*16 + quad*4
    float4 bv[8];
#pragma unroll
    for (int mt = 0; mt < 8; ++mt)
        bv[mt] = *(const float4*)(b1 + mt * 16 + quad * 4);

    unsigned short* hb = &h_lds[w][0];

    // lane-constant staging coords: float4 f = i*64+lane; row=f>>5, c4=f&31
    int srow[8], sc4[8];
#pragma unroll
    for (int i = 0; i < 8; ++i) { int f = i * 64 + lane; srow[i] = f >> 5; sc4[i] = f & 31; }

#define LOADH(PF, T)                                                           \
    _Pragma("unroll") for (int i = 0; i < 8; ++i)                              \
        PF[i] = *(const float4*)(h + ((size_t)(T) * 16 + srow[i]) * F + sc4[i] * 4);

#define CVTWRITE(PF, DST)                                                      \
    _Pragma("unroll") for (int i = 0; i < 8; ++i) {                            \
        uint2 p;                                                               \
        p.x = (unsigned)f2bf(PF[i].x) | ((unsigned)f2bf(PF[i].y) << 16);       \
        p.y = (unsigned)f2bf(PF[i].z) | ((unsigned)f2bf(PF[i].w) << 16);       \
        *(uint2*)&(DST)[srow[i] * 136 + sc4[i] * 4] = p;                       \
    }

    int t = blockIdx.x * 8 + w;           // 2048 wave-slots over 6250 tiles
    bool act = (t < NT);
    float4 pf[8];
    if (act) { LOADH(pf, t); CVTWRITE(pf, hb); }

    while (act) {
        const int tn = t + 2048;
        const bool actn = (tn < NT);
        if (actn) LOADH(pf, tn);          // prefetch next tile (global, coalesced)

        // ---- compute tile t: both A and B halves ----
        float4v acc[16];
#pragma unroll
        for (int mt = 0; mt < 16; ++mt) acc[mt] = (float4v){0.f, 0.f, 0.f, 0.f};
#pragma unroll
        for (int k0 = 0; k0 < 4; ++k0) {
            const int kb = k0 * 32 + quad * 8;
            short8 bf = *(const short8*)&hb[l16 * 136 + kb];
#pragma unroll
            for (int mt = 0; mt < 16; ++mt) {
                short8 af = *(const short8*)&w_lds[(mt * 16 + l16) * 136 + kb];
                acc[mt] = __builtin_amdgcn_mfma_f32_16x16x32_bf16(af, bf, acc[mt], 0, 0, 0);
            }
        }

        // ---- stage prefetched tile into the same buffer (after all reads) ----
        if (actn) CVTWRITE(pf, hb);

        // ---- epilogue: node = t*16 + l16; mt<8 -> A (+bias), mt>=8 -> B ----
        {
            const size_t nodeoff = ((size_t)t * 16 + l16) * F;
#pragma unroll
            for (int mt = 0; mt < 8; ++mt) {
                const int col = mt * 16 + quad * 4;
                ushort4 sv;
                sv.x = f2bf(acc[mt][0] + bv[mt].x);
                sv.y = f2bf(acc[mt][1] + bv[mt].y);
                sv.z = f2bf(acc[mt][2] + bv[mt].z);
                sv.w = f2bf(acc[mt][3] + bv[mt].w);
                *(ushort4*)(A + nodeoff + col) = sv;
            }
#pragma unroll
            for (int mt = 8; mt < 16; ++mt) {
                const int col = (mt - 8) * 16 + quad * 4;
                ushort4 sv;
                sv.x = f2bf(acc[mt][0]);
                sv.y = f2bf(acc[mt][1]);
                sv.z = f2bf(acc[mt][2]);
                sv.w = f2bf(acc[mt][3]);
                *(ushort4*)(B + nodeoff + col) = sv;
            }
        }
        t = tn; act = actn;
    }
#undef LOADH
#undef CVTWRITE
}

// ---------------------------------------------------------------------------
// Kernel 2: per-edge score from bf16 A,B. (round-5 best; at the unique-line
// service wall ~45 us — warm-cache replay identical to cold, r7 evidence)
// ---------------------------------------------------------------------------
__global__ __launch_bounds__(256) void edge_score(
    const unsigned short* __restrict__ A, const unsigned short* __restrict__ B,
    const int* __restrict__ src, const int* __restrict__ dst,
    const float* __restrict__ W2, const float* __restrict__ b2,
    float* __restrict__ out)
{
    const int tid = threadIdx.x;
    const int sub = tid & 7;
    const int e0  = blockIdx.x * 128 + (tid >> 3) * 4;
    const int j0  = sub * 16;

    const int4 sv = *(const int4*)(src + e0);
    const int4 dv = *(const int4*)(dst + e0);
    const int s[4] = {sv.x, sv.y, sv.z, sv.w};
    const int d[4] = {dv.x, dv.y, dv.z, dv.w};

    uint4 av0[4], av1[4], bv0[4], bv1[4];
#pragma unroll
    for (int i = 0; i < 4; ++i) {
        const uint4* Ap = (const uint4*)(A + (size_t)s[i] * F + j0);
        const uint4* Bp = (const uint4*)(B + (size_t)d[i] * F + j0);
        av0[i] = Ap[0]; av1[i] = Ap[1];
        bv0[i] = Bp[0]; bv1[i] = Bp[1];
    }

    const float4* Wp = (const float4*)(W2 + j0);
    const float4 w0 = Wp[0], w1 = Wp[1], w2 = Wp[2], w3 = Wp[3];
    const float bias = b2[0];

#define TERM(UA, UB, WL, WH)                                                   \
    {                                                                          \
        float fa0 = __uint_as_float((UA) << 16);                               \
        float fa1 = __uint_as_float((UA) & 0xFFFF0000u);                       \
        float fb0 = __uint_as_float((UB) << 16);                               \
        float fb1 = __uint_as_float((UB) & 0xFFFF0000u);                       \
        sacc = fmaf(fmaxf(fa0 + fb0, 0.f), (WL), sacc);                        \
        sacc = fmaf(fmaxf(fa1 + fb1, 0.f), (WH), sacc);                        \
    }
#pragma unroll
    for (int i = 0; i < 4; ++i) {
        float sacc = 0.f;
        TERM(av0[i].x, bv0[i].x, w0.x, w0.y)
        TERM(av0[i].y, bv0[i].y, w0.z, w0.w)
        TERM(av0[i].z, bv0[i].z, w1.x, w1.y)
        TERM(av0[i].w, bv0[i].w, w1.z, w1.w)
        TERM(av1[i].x, bv1[i].x, w2.x, w2.y)
        TERM(av1[i].y, bv1[i].y, w2.z, w2.w)
        TERM(av1[i].z, bv1[i].z, w3.x, w3.y)
        TERM(av1[i].w, bv1[i].w, w3.z, w3.w)
        sacc += __shfl_xor(sacc, 1);
        sacc += __shfl_xor(sacc, 2);
        sacc += __shfl_xor(sacc, 4);
        if (sub == 0) out[e0 + i] = sacc + bias;
    }
#undef TERM
}

extern "C" void kernel_launch(void* const* d_in, const int* in_sizes, int n_in,
                              void* d_out, int out_size, void* d_ws, size_t ws_size,
                              hipStream_t stream) {
    const float* h   = (const float*)d_in[0];
    const int*   src = (const int*)d_in[1];
    const int*   dst = (const int*)d_in[2];
    const float* W1  = (const float*)d_in[3];
    const float* b1  = (const float*)d_in[4];
    const float* W2  = (const float*)d_in[5];
    const float* b2  = (const float*)d_in[6];
    float* out = (float*)d_out;

    // workspace layout (bf16): Wt[256][128] | A[100000][128] | B[100000][128]
    unsigned short* Wt = (unsigned short*)d_ws;
    unsigned short* A  = Wt + 256 * 128;
    unsigned short* B  = A + (size_t)N_NODES * F;

    prep_wt<<<128, 256, 0, stream>>>(W1, Wt);
    node_proj<<<256, 512, 0, stream>>>(h, Wt, b1, A, B);
    edge_score<<<N_EDGES / 128, 256, 0, stream>>>(A, B, src, dst, W2, b2, out);
}

// Round 9
// 160.697 us; speedup vs baseline: 1.6373x; 1.6373x over previous
//
#include <hip/hip_runtime.h>

#define N_NODES 100000
#define N_EDGES 640000
#define F 128
#define NT 6250          // 16-node tiles (100000 = 6250*16 exactly)
#define NBLK 512         // node_proj blocks; tiles stride NBLK

typedef __attribute__((ext_vector_type(8))) short short8;
typedef __attribute__((ext_vector_type(4))) float float4v;

// RNE float -> bf16 bits
static __device__ __forceinline__ unsigned short f2bf(float f) {
    unsigned int u = __float_as_uint(f);
    u += 0x7fffu + ((u >> 16) & 1u);
    return (unsigned short)(u >> 16);
}

// ---------------------------------------------------------------------------
// Kernel 0: transpose+convert W1 (fp32 [256][128]) into Wt bf16 [256][128]:
//   Wt[n][k] = W1[(n&128)+k][n&127]
// n<128 rows = A-half (W1[k][n]); n>=128 = B-half. 64 KB, stays L2-hot.
// ---------------------------------------------------------------------------
__global__ __launch_bounds__(256) void prep_wt(
    const float* __restrict__ W1, unsigned short* __restrict__ Wt)
{
    int id = blockIdx.x * 256 + threadIdx.x;       // 0 .. 32767
    int n = id >> 7, k = id & 127;
    float v = W1[((n & 128) + k) * 128 + (n & 127)];
    Wt[id] = f2bf(v);
}

// ---------------------------------------------------------------------------
// Kernel 1: node projections — fused A+B, single pass over h, 2 blocks/CU.
// (r8 post-mortem: 1 block/CU + sparse tiles = write-allocate RMW storm;
//  this keeps r7's density/occupancy while reading h once.)
//   512 blocks x 256 threads (4 waves). Full Wt (256x136) in LDS (69.6 KB)
//   + shared double-buffered 16-node h tile (2 x 4.35 KB) = 78.3 KB
//   -> 2 blocks/CU. Wave w: wcols [w*64, w*64+64); w<2 -> A (+b1), w>=2 -> B.
//   Per tile: prefetch h(t+NBLK) to regs (coalesced float4, 2/thread) ->
//   MFMA tile t from hb[cur] -> cvt+write prefetch to hb[cur^1] -> stores ->
//   ONE __syncthreads. Double-buffer hazards covered by the single barrier.
//   mfma_16x16x32_bf16 (r7-verified): A-frag = w_lds row (m=wcol, l16),
//   B-frag = hb row (n=node, l16); C/D: wcol=quad*4+reg, node=l16.
// ---------------------------------------------------------------------------
__global__ __launch_bounds__(256, 2) void node_proj(
    const float* __restrict__ h, const unsigned short* __restrict__ Wt,
    const float* __restrict__ b1,
    unsigned short* __restrict__ A, unsigned short* __restrict__ B)
{
    __shared__ unsigned short w_lds[256 * 136];      // 69.6 KB
    __shared__ unsigned short h_lds[2][16 * 136];    // 8.7 KB

    const int tid  = threadIdx.x;
    const int lane = tid & 63;
    const int l16  = lane & 15;
    const int quad = lane >> 4;
    const int w    = tid >> 6;            // wave id 0..3

    // ---- stage full Wt into LDS, fully coalesced (uint4 = 8 bf16) ----
#pragma unroll
    for (int i = 0; i < 16; ++i) {
        int c = i * 256 + tid;            // uint4 chunk id, 0..4095
        int r = c >> 4, cc = c & 15;      // 16 chunks per 128-short row
        uint4 v = *(const uint4*)(Wt + (size_t)r * F + cc * 8);
        *(uint4*)&w_lds[r * 136 + cc * 8] = v;
    }

    // hoisted bias fragments: wave w<2 -> A cols w*64 + p*16 + quad*4
    const bool isA = (w < 2);
    float4 bv[4];
#pragma unroll
    for (int p = 0; p < 4; ++p) {
        int col = (w & 1) * 64 + p * 16 + quad * 4;
        bv[p] = isA ? *(const float4*)(b1 + col) : make_float4(0.f, 0.f, 0.f, 0.f);
    }
    unsigned short* outp = isA ? A : B;
    const int colb = (w & 1) * 64;

    // staging coords: float4 f = i*256+tid, i<2; row=f>>5 (0..15), c4=f&31
    int srow[2], sc4[2];
#pragma unroll
    for (int i = 0; i < 2; ++i) { int f = i * 256 + tid; srow[i] = f >> 5; sc4[i] = f & 31; }

#define LOADH(PF, T)                                                           \
    _Pragma("unroll") for (int i = 0; i < 2; ++i)                              \
        PF[i] = *(const float4*)(h + ((size_t)(T) * 16 + srow[i]) * F + sc4[i] * 4);

#define CVTWRITE(PF, DST)                                                      \
    _Pragma("unroll") for (int i = 0; i < 2; ++i) {                            \
        uint2 p;                                                               \
        p.x = (unsigned)f2bf(PF[i].x) | ((unsigned)f2bf(PF[i].y) << 16);       \
        p.y = (unsigned)f2bf(PF[i].z) | ((unsigned)f2bf(PF[i].w) << 16);       \
        *(uint2*)&(DST)[srow[i] * 136 + sc4[i] * 4] = p;                       \
    }

    int t = blockIdx.x;                   // tiles t, t+512, ... (dense)
    float4 pf[2];
    if (t < NT) { LOADH(pf, t); CVTWRITE(pf, h_lds[0]); }
    __syncthreads();                      // covers Wt stage + tile 0

    int cur = 0;
    while (t < NT) {
        const int tn = t + NBLK;
        const bool actn = (tn < NT);
        if (actn) LOADH(pf, tn);          // prefetch next tile (global, coalesced)

        // ---- compute tile t: wave's 4 wtiles ----
        const unsigned short* hb = h_lds[cur];
        float4v acc[4];
#pragma unroll
        for (int p = 0; p < 4; ++p) acc[p] = (float4v){0.f, 0.f, 0.f, 0.f};
#pragma unroll
        for (int k0 = 0; k0 < 4; ++k0) {
            const int kb = k0 * 32 + quad * 8;
            short8 bf = *(const short8*)&hb[l16 * 136 + kb];
#pragma unroll
            for (int p = 0; p < 4; ++p) {
                short8 af = *(const short8*)&w_lds[(w * 64 + p * 16 + l16) * 136 + kb];
                acc[p] = __builtin_amdgcn_mfma_f32_16x16x32_bf16(af, bf, acc[p], 0, 0, 0);
            }
        }

        // ---- stage prefetched tile into the other buffer ----
        if (actn) CVTWRITE(pf, h_lds[cur ^ 1]);

        // ---- epilogue: node = t*16 + l16; cols colb + p*16 + quad*4 ----
        {
            const size_t nodeoff = ((size_t)t * 16 + l16) * F;
#pragma unroll
            for (int p = 0; p < 4; ++p) {
                ushort4 sv;
                sv.x = f2bf(acc[p][0] + bv[p].x);
                sv.y = f2bf(acc[p][1] + bv[p].y);
                sv.z = f2bf(acc[p][2] + bv[p].z);
                sv.w = f2bf(acc[p][3] + bv[p].w);
                *(ushort4*)(outp + nodeoff + colb + p * 16 + quad * 4) = sv;
            }
        }
        __syncthreads();                  // the ONE per-tile barrier
        cur ^= 1; t = tn;
    }
#undef LOADH
#undef CVTWRITE
}

// ---------------------------------------------------------------------------
// Kernel 2: per-edge score from bf16 A,B. (round-5 best; at the unique-line
// service wall ~45 us — warm-cache replay identical to cold, r7 evidence)
// ---------------------------------------------------------------------------
__global__ __launch_bounds__(256) void edge_score(
    const unsigned short* __restrict__ A, const unsigned short* __restrict__ B,
    const int* __restrict__ src, const int* __restrict__ dst,
    const float* __restrict__ W2, const float* __restrict__ b2,
    float* __restrict__ out)
{
    const int tid = threadIdx.x;
    const int sub = tid & 7;
    const int e0  = blockIdx.x * 128 + (tid >> 3) * 4;
    const int j0  = sub * 16;

    const int4 sv = *(const int4*)(src + e0);
    const int4 dv = *(const int4*)(dst + e0);
    const int s[4] = {sv.x, sv.y, sv.z, sv.w};
    const int d[4] = {dv.x, dv.y, dv.z, dv.w};

    uint4 av0[4], av1[4], bv0[4], bv1[4];
#pragma unroll
    for (int i = 0; i < 4; ++i) {
        const uint4* Ap = (const uint4*)(A + (size_t)s[i] * F + j0);
        const uint4* Bp = (const uint4*)(B + (size_t)d[i] * F + j0);
        av0[i] = Ap[0]; av1[i] = Ap[1];
        bv0[i] = Bp[0]; bv1[i] = Bp[1];
    }

    const float4* Wp = (const float4*)(W2 + j0);
    const float4 w0 = Wp[0], w1 = Wp[1], w2 = Wp[2], w3 = Wp[3];
    const float bias = b2[0];

#define TERM(UA, UB, WL, WH)                                                   \
    {                                                                          \
        float fa0 = __uint_as_float((UA) << 16);                               \
        float fa1 = __uint_as_float((UA) & 0xFFFF0000u);                       \
        float fb0 = __uint_as_float((UB) << 16);                               \
        float fb1 = __uint_as_float((UB) & 0xFFFF0000u);                       \
        sacc = fmaf(fmaxf(fa0 + fb0, 0.f), (WL), sacc);                        \
        sacc = fmaf(fmaxf(fa1 + fb1, 0.f), (WH), sacc);                        \
    }
#pragma unroll
    for (int i = 0; i < 4; ++i) {
        float sacc = 0.f;
        TERM(av0[i].x, bv0[i].x, w0.x, w0.y)
        TERM(av0[i].y, bv0[i].y, w0.z, w0.w)
        TERM(av0[i].z, bv0[i].z, w1.x, w1.y)
        TERM(av0[i].w, bv0[i].w, w1.z, w1.w)
        TERM(av1[i].x, bv1[i].x, w2.x, w2.y)
        TERM(av1[i].y, bv1[i].y, w2.z, w2.w)
        TERM(av1[i].z, bv1[i].z, w3.x, w3.y)
        TERM(av1[i].w, bv1[i].w, w3.z, w3.w)
        sacc += __shfl_xor(sacc, 1);
        sacc += __shfl_xor(sacc, 2);
        sacc += __shfl_xor(sacc, 4);
        if (sub == 0) out[e0 + i] = sacc + bias;
    }
#undef TERM
}

extern "C" void kernel_launch(void* const* d_in, const int* in_sizes, int n_in,
                              void* d_out, int out_size, void* d_ws, size_t ws_size,
                              hipStream_t stream) {
    const float* h   = (const float*)d_in[0];
    const int*   src = (const int*)d_in[1];
    const int*   dst = (const int*)d_in[2];
    const float* W1  = (const float*)d_in[3];
    const float* b1  = (const float*)d_in[4];
    const float* W2  = (const float*)d_in[5];
    const float* b2  = (const float*)d_in[6];
    float* out = (float*)d_out;

    // workspace layout (bf16): Wt[256][128] | A[100000][128] | B[100000][128]
    unsigned short* Wt = (unsigned short*)d_ws;
    unsigned short* A  = Wt + 256 * 128;
    unsigned short* B  = A + (size_t)N_NODES * F;

    prep_wt<<<128, 256, 0, stream>>>(W1, Wt);
    node_proj<<<NBLK, 256, 0, stream>>>(h, Wt, b1, A, B);
    edge_score<<<N_EDGES / 128, 256, 0, stream>>>(A, B, src, dst, W2, b2, out);
}

// Round 10
// 154.707 us; speedup vs baseline: 1.7007x; 1.0387x over previous
//
#include <hip/hip_runtime.h>

#define N_NODES 100000
#define N_EDGES 640000
#define F 128
#define NT 6250          // 16-node tiles (100000 = 6250*16 exactly)
#define NBLK 512         // node_proj blocks; tiles stride NBLK

typedef __attribute__((ext_vector_type(8))) short short8;
typedef __attribute__((ext_vector_type(4))) float float4v;

// RNE float -> bf16 bits
static __device__ __forceinline__ unsigned short f2bf(float f) {
    unsigned int u = __float_as_uint(f);
    u += 0x7fffu + ((u >> 16) & 1u);
    return (unsigned short)(u >> 16);
}

// ---------------------------------------------------------------------------
// Kernel 0: transpose+convert W1 (fp32 [256][128]) into Wt bf16 [256][128]:
//   Wt[n][k] = W1[(n&128)+k][n&127]
// ---------------------------------------------------------------------------
__global__ __launch_bounds__(256) void prep_wt(
    const float* __restrict__ W1, unsigned short* __restrict__ Wt)
{
    int id = blockIdx.x * 256 + threadIdx.x;       // 0 .. 32767
    int n = id >> 7, k = id & 127;
    float v = W1[((n & 128) + k) * 128 + (n & 127)];
    Wt[id] = f2bf(v);
}

// ---------------------------------------------------------------------------
// Kernel 1: node projections — fused A+B, single pass over h, 2 blocks/CU,
// XOR-swizzled Wt LDS (64 KB, no pad) + LDS-staged contiguous epilogue.
//   Wt chunk layout: 16B chunk (r,c) lives at chunk slot r*16 + (c ^ (r&15)).
//     af read banks: chunk' = (k0*4+quad)^l16 -> 2 lanes/4-bank group = free.
//   Per tile (2 barriers):
//     MFMA(hb) -> B1 -> write next-h into hb + stage acc->oA/oB -> B2 ->
//     row-contiguous uint4 global stores (4 full 256B rows per instruction,
//     r8/r9 evidence: 8B x 16-row scatter caused write-allocate RMW).
// LDS: 64 (Wt) + 4.25 (hb) + 2x4.25 (oA,oB) = 76.8 KB -> 2 blocks/CU.
// ---------------------------------------------------------------------------
__global__ __launch_bounds__(256, 2) void node_proj(
    const float* __restrict__ h, const unsigned short* __restrict__ Wt,
    const float* __restrict__ b1,
    unsigned short* __restrict__ A, unsigned short* __restrict__ B)
{
    __shared__ unsigned short w_swz[256 * 128];   // 64 KB, swizzled chunks
    __shared__ unsigned short hb[16 * 136];       // h tile (padded rows)
    __shared__ unsigned short oA[16 * 136];       // A out-stage
    __shared__ unsigned short oB[16 * 136];       // B out-stage

    const int tid  = threadIdx.x;
    const int lane = tid & 63;
    const int l16  = lane & 15;
    const int quad = lane >> 4;
    const int w    = tid >> 6;            // wave id 0..3

    // ---- stage full Wt into swizzled LDS (coalesced global reads) ----
#pragma unroll
    for (int i = 0; i < 16; ++i) {
        int cl = i * 256 + tid;           // chunk id 0..4095
        int r = cl >> 4, c = cl & 15;
        uint4 v = *(const uint4*)(Wt + (size_t)r * F + c * 8);
        *(uint4*)&w_swz[((r << 4) + (c ^ (r & 15))) * 8] = v;
    }

    // bias frags: waves 0,1 own A cols (w&1)*64 + p*16 + quad*4
    const bool isA = (w < 2);
    const int colb = (w & 1) * 64;
    float4 bv[4];
#pragma unroll
    for (int p = 0; p < 4; ++p) {
        int col = colb + p * 16 + quad * 4;
        bv[p] = isA ? *(const float4*)(b1 + col) : make_float4(0.f, 0.f, 0.f, 0.f);
    }
    unsigned short* ostage = isA ? oA : oB;

    // staging coords: float4 f = i*256+tid, i<2; row=f>>5 (0..15), c4=f&31
    int srow[2], sc4[2];
#pragma unroll
    for (int i = 0; i < 2; ++i) { int f = i * 256 + tid; srow[i] = f >> 5; sc4[i] = f & 31; }

#define LOADH(PF, T)                                                           \
    _Pragma("unroll") for (int i = 0; i < 2; ++i)                              \
        PF[i] = *(const float4*)(h + ((size_t)(T) * 16 + srow[i]) * F + sc4[i] * 4);

#define CVTWRITE(PF)                                                           \
    _Pragma("unroll") for (int i = 0; i < 2; ++i) {                            \
        uint2 p;                                                               \
        p.x = (unsigned)f2bf(PF[i].x) | ((unsigned)f2bf(PF[i].y) << 16);       \
        p.y = (unsigned)f2bf(PF[i].z) | ((unsigned)f2bf(PF[i].w) << 16);       \
        *(uint2*)&hb[srow[i] * 136 + sc4[i] * 4] = p;                          \
    }

    int t = blockIdx.x;                   // 512 < 6250: tile 0 always valid
    float4 pf[2];
    LOADH(pf, t); CVTWRITE(pf);
    __syncthreads();                      // Wt + tile 0 staged

    while (t < NT) {
        const int tn = t + NBLK;
        const bool actn = (tn < NT);
        if (actn) LOADH(pf, tn);          // prefetch next tile into regs

        // ---- MFMA tile t: wave w -> wcols w*64 .. w*64+63 ----
        float4v acc[4];
#pragma unroll
        for (int p = 0; p < 4; ++p) acc[p] = (float4v){0.f, 0.f, 0.f, 0.f};
#pragma unroll
        for (int k0 = 0; k0 < 4; ++k0) {
            short8 bf = *(const short8*)&hb[l16 * 136 + k0 * 32 + quad * 8];
            const int cc = (k0 * 4 + quad);
#pragma unroll
            for (int p = 0; p < 4; ++p) {
                const int row = w * 64 + p * 16 + l16;     // row & 15 == l16
                short8 af = *(const short8*)&w_swz[((row << 4) + (cc ^ l16)) * 8];
                acc[p] = __builtin_amdgcn_mfma_f32_16x16x32_bf16(af, bf, acc[p], 0, 0, 0);
            }
        }
        __syncthreads();                  // B1: hb(t) + oX(t-1) reads done

        if (actn) CVTWRITE(pf);           // next h tile into hb
        // stage acc -> out LDS (node=l16 row, bias folded here)
#pragma unroll
        for (int p = 0; p < 4; ++p) {
            ushort4 sv;
            sv.x = f2bf(acc[p][0] + bv[p].x);
            sv.y = f2bf(acc[p][1] + bv[p].y);
            sv.z = f2bf(acc[p][2] + bv[p].z);
            sv.w = f2bf(acc[p][3] + bv[p].w);
            *(ushort4*)&ostage[l16 * 136 + colb + p * 16 + quad * 4] = sv;
        }
        __syncthreads();                  // B2: hb(t+1) + oX(t) written

        // ---- contiguous stores: thread tid -> row tid>>4, chunk tid&15 ----
        {
            const int r = tid >> 4, c = tid & 15;
            const size_t goff = ((size_t)t * 16 + r) * F + c * 8;
            *(uint4*)(A + goff) = *(const uint4*)&oA[r * 136 + c * 8];
            *(uint4*)(B + goff) = *(const uint4*)&oB[r * 136 + c * 8];
        }
        t = tn;
    }
#undef LOADH
#undef CVTWRITE
}

// ---------------------------------------------------------------------------
// Kernel 2: per-edge score. CONTIGUOUS-CHUNK reindex (discriminating exp):
//   lane sub covers channels [sub*8, sub*8+8) and [64+sub*8, +8) -> each
//   load instruction's 8 lanes read 128 CONTIGUOUS bytes per row (2 lines)
//   instead of stride-32 spray over all 4 lines. Halves line transactions
//   per instruction; if edge is transaction-bound -> ~2x, if byte-bound -> 0.
// ---------------------------------------------------------------------------
__global__ __launch_bounds__(256) void edge_score(
    const unsigned short* __restrict__ A, const unsigned short* __restrict__ B,
    const int* __restrict__ src, const int* __restrict__ dst,
    const float* __restrict__ W2, const float* __restrict__ b2,
    float* __restrict__ out)
{
    const int tid = threadIdx.x;
    const int sub = tid & 7;
    const int e0  = blockIdx.x * 128 + (tid >> 3) * 4;

    const int4 sv = *(const int4*)(src + e0);
    const int4 dv = *(const int4*)(dst + e0);
    const int s[4] = {sv.x, sv.y, sv.z, sv.w};
    const int d[4] = {dv.x, dv.y, dv.z, dv.w};

    uint4 av0[4], av1[4], bv0[4], bv1[4];
#pragma unroll
    for (int i = 0; i < 4; ++i) {
        const unsigned short* Ar = A + (size_t)s[i] * F;
        const unsigned short* Br = B + (size_t)d[i] * F;
        av0[i] = *(const uint4*)(Ar + sub * 8);        // ch sub*8..+7
        av1[i] = *(const uint4*)(Ar + 64 + sub * 8);   // ch 64+sub*8..+7
        bv0[i] = *(const uint4*)(Br + sub * 8);
        bv1[i] = *(const uint4*)(Br + 64 + sub * 8);
    }

    const float4 w0 = *(const float4*)(W2 + sub * 8);
    const float4 w1 = *(const float4*)(W2 + sub * 8 + 4);
    const float4 w2 = *(const float4*)(W2 + 64 + sub * 8);
    const float4 w3 = *(const float4*)(W2 + 64 + sub * 8 + 4);
    const float bias = b2[0];

#define TERM(UA, UB, WL, WH)                                                   \
    {                                                                          \
        float fa0 = __uint_as_float((UA) << 16);                               \
        float fa1 = __uint_as_float((UA) & 0xFFFF0000u);                       \
        float fb0 = __uint_as_float((UB) << 16);                               \
        float fb1 = __uint_as_float((UB) & 0xFFFF0000u);                       \
        sacc = fmaf(fmaxf(fa0 + fb0, 0.f), (WL), sacc);                        \
        sacc = fmaf(fmaxf(fa1 + fb1, 0.f), (WH), sacc);                        \
    }
#pragma unroll
    for (int i = 0; i < 4; ++i) {
        float sacc = 0.f;
        TERM(av0[i].x, bv0[i].x, w0.x, w0.y)
        TERM(av0[i].y, bv0[i].y, w0.z, w0.w)
        TERM(av0[i].z, bv0[i].z, w1.x, w1.y)
        TERM(av0[i].w, bv0[i].w, w1.z, w1.w)
        TERM(av1[i].x, bv1[i].x, w2.x, w2.y)
        TERM(av1[i].y, bv1[i].y, w2.z, w2.w)
        TERM(av1[i].z, bv1[i].z, w3.x, w3.y)
        TERM(av1[i].w, bv1[i].w, w3.z, w3.w)
        sacc += __shfl_xor(sacc, 1);
        sacc += __shfl_xor(sacc, 2);
        sacc += __shfl_xor(sacc, 4);
        if (sub == 0) out[e0 + i] = sacc + bias;
    }
#undef TERM
}

extern "C" void kernel_launch(void* const* d_in, const int* in_sizes, int n_in,
                              void* d_out, int out_size, void* d_ws, size_t ws_size,
                              hipStream_t stream) {
    const float* h   = (const float*)d_in[0];
    const int*   src = (const int*)d_in[1];
    const int*   dst = (const int*)d_in[2];
    const float* W1  = (const float*)d_in[3];
    const float* b1  = (const float*)d_in[4];
    const float* W2  = (const float*)d_in[5];
    const float* b2  = (const float*)d_in[6];
    float* out = (float*)d_out;

    // workspace layout (bf16): Wt[256][128] | A[100000][128] | B[100000][128]
    unsigned short* Wt = (unsigned short*)d_ws;
    unsigned short* A  = Wt + 256 * 128;
    unsigned short* B  = A + (size_t)N_NODES * F;

    prep_wt<<<128, 256, 0, stream>>>(W1, Wt);
    node_proj<<<NBLK, 256, 0, stream>>>(h, Wt, b1, A, B);
    edge_score<<<N_EDGES / 128, 256, 0, stream>>>(A, B, src, dst, W2, b2, out);
}